// Round 9
// baseline (1236.584 us; speedup 1.0000x reference)
//
#include <hip/hip_runtime.h>
#include <hip/hip_bf16.h>

#define NN 50000
#define NE 800000
#define DD 64
#define NEG 0.2f

#define RFL(x) __builtin_amdgcn_readfirstlane(x)

// ---------------- CSR build ----------------
__global__ void k_hist(const int* __restrict__ dst1, const int* __restrict__ dst2,
                       int* __restrict__ cnt1, int* __restrict__ cnt2) {
    int e = blockIdx.x * blockDim.x + threadIdx.x;
    if (e < NE) {
        atomicAdd(&cnt1[dst1[e]], 1);
        atomicAdd(&cnt2[dst2[e]], 1);
    }
}

__global__ __launch_bounds__(1024) void k_scan(const int* __restrict__ cnt1, int* __restrict__ off1,
                                               const int* __restrict__ cnt2, int* __restrict__ off2) {
    const int* cnt = blockIdx.x ? cnt2 : cnt1;
    int* off = blockIdx.x ? off2 : off1;
    __shared__ int lds[1024];
    const int tid = threadIdx.x;
    const int CH = (NN + 1023) / 1024;  // 49
    const int base = tid * CH;
    int s = 0;
    for (int q = 0; q < CH; ++q) {
        int idx = base + q;
        if (idx < NN) s += cnt[idx];
    }
    lds[tid] = s;
    __syncthreads();
    for (int d = 1; d < 1024; d <<= 1) {
        int v = (tid >= d) ? lds[tid - d] : 0;
        __syncthreads();
        lds[tid] += v;
        __syncthreads();
    }
    int run = tid ? lds[tid - 1] : 0;
    for (int q = 0; q < CH; ++q) {
        int idx = base + q;
        if (idx < NN) { off[idx] = run; run += cnt[idx]; }
    }
    if (tid == 1023) off[NN] = lds[1023];
}

__global__ void k_scatter(const int* __restrict__ src1, const int* __restrict__ dst1,
                          const int* __restrict__ off1, int* __restrict__ fill1, int* __restrict__ csr1,
                          const int* __restrict__ src2, const int* __restrict__ dst2,
                          const int* __restrict__ off2, int* __restrict__ fill2, int* __restrict__ csr2) {
    int e = blockIdx.x * blockDim.x + threadIdx.x;
    if (e < NE) {
        int d1 = dst1[e];
        int p1 = off1[d1] + atomicAdd(&fill1[d1], 1);
        csr1[p1] = src1[e];
        int d2 = dst2[e];
        int p2 = off2[d2] + atomicAdd(&fill2[d2], 1);
        csr2[p2] = src2[e];
    }
}

// ---------------- H1 = x @ W1, alpha1 = H1 @ a1_{src,dst} ----------------
__global__ __launch_bounds__(256) void k_h1(
    const float* __restrict__ x, const float* __restrict__ W1,
    const float* __restrict__ a1s, const float* __restrict__ a1d,
    float* __restrict__ H1, float* __restrict__ al1s, float* __restrict__ al1d) {
    const int lane = threadIdx.x & 63;
    const int i = blockIdx.x * 4 + (threadIdx.x >> 6);
    const float xv = x[i * DD + lane];
    float h = 0.f;
#pragma unroll
    for (int j = 0; j < DD; ++j) h = fmaf(__shfl(xv, j), W1[j * DD + lane], h);
    H1[i * DD + lane] = h;
    float ps = h * a1s[lane], pd = h * a1d[lane];
#pragma unroll
    for (int o = 32; o; o >>= 1) { ps += __shfl_xor(ps, o); pd += __shfl_xor(pd, o); }
    if (lane == 0) { al1s[i] = ps; al1d[i] = pd; }
}

// ---- layer1: 16-lane groups, 4 edges per wave-iteration ----
__global__ __launch_bounds__(256) void k_l1(
    const int* __restrict__ off, const int* __restrict__ csrc,
    const float* __restrict__ al1s, const float* __restrict__ al1d,
    const float* __restrict__ H1,
    const float* __restrict__ W2, const float* __restrict__ a2s, const float* __restrict__ a2d,
    uint4* __restrict__ H2a, _Float16* __restrict__ H2b,
    float* __restrict__ al2s8, float* __restrict__ al2s9, float* __restrict__ al2d) {
    const int lane = threadIdx.x & 63;
    const int i = blockIdx.x * 4 + (threadIdx.x >> 6);
    const int g = lane >> 4, q = lane & 15;
    const int p0 = RFL(off[i]);
    const int p1 = RFL(off[i + 1]);
    const float adv = al1d[i];

    float4 n4[9]; float den[9];
#pragma unroll
    for (int k = 0; k < 9; ++k) { n4[k] = make_float4(0.f, 0.f, 0.f, 0.f); den[k] = 0.f; }

    for (int p = p0; p < p1; p += 4) {
        int e = p + g;
        float mask = 1.f;
        if (e >= p1) { e = p1 - 1; mask = 0.f; }
        int s = csrc[e];                              // group-uniform broadcast load
        float z = al1s[s] + adv;
        float c = z > 0.f ? z : NEG * z;              // leaky_relu (step-invariant)
        float rv = __expf(c * (1.f / 9.f)) * mask;    // w_k = rv^k
        const float4 h4 = *reinterpret_cast<const float4*>(H1 + (size_t)s * DD + q * 4);
        float w = rv;
#pragma unroll
        for (int k = 0; k < 9; ++k) {
            den[k] += w;
            n4[k].x = fmaf(w, h4.x, n4[k].x);
            n4[k].y = fmaf(w, h4.y, n4[k].y);
            n4[k].z = fmaf(w, h4.z, n4[k].z);
            n4[k].w = fmaf(w, h4.w, n4[k].w);
            w *= rv;
        }
    }
    // reduce across the 4 groups (within-group copies are identical for den)
#pragma unroll
    for (int k = 0; k < 9; ++k) {
#pragma unroll
        for (int o = 16; o <= 32; o <<= 1) {
            n4[k].x += __shfl_xor(n4[k].x, o);
            n4[k].y += __shfl_xor(n4[k].y, o);
            n4[k].z += __shfl_xor(n4[k].z, o);
            n4[k].w += __shfl_xor(n4[k].w, o);
            den[k]  += __shfl_xor(den[k], o);
        }
    }
    // transpose to dim==lane scalar layout + softmax-normalize + ELU
    const int srcl = lane >> 2, sel = lane & 3;
    float hm[9];
#pragma unroll
    for (int k = 0; k < 9; ++k) {
        float a = __shfl(n4[k].x, srcl);
        float b = __shfl(n4[k].y, srcl);
        float c = __shfl(n4[k].z, srcl);
        float d = __shfl(n4[k].w, srcl);
        float nm = sel == 0 ? a : sel == 1 ? b : sel == 2 ? c : d;
        float t = (float)(k + 1) * (1.f / 9.f);
        float v = (den[k] > 0.f) ? (t * nm / den[k]) : 0.f;
        hm[k] = (v > 0.f) ? v : (__expf(v) - 1.f);    // ELU
    }
    // h2[k] = sum_j hm[k][j] * W2[j][lane]
    float h2[9];
#pragma unroll
    for (int k = 0; k < 9; ++k) h2[k] = 0.f;
#pragma unroll
    for (int j = 0; j < DD; ++j) {
        float wj = W2[j * DD + lane];
#pragma unroll
        for (int k = 0; k < 9; ++k) h2[k] = fmaf(__shfl(hm[k], j), wj, h2[k]);
    }
    const float a2sv = a2s[lane];
    const float a2dv = a2d[lane];
#pragma unroll
    for (int k = 0; k < 9; ++k) {
        float ps = h2[k] * a2sv, pd = h2[k] * a2dv;
#pragma unroll
        for (int o = 32; o; o >>= 1) { ps += __shfl_xor(ps, o); pd += __shfl_xor(pd, o); }
        if (lane == 0) {
            if (k < 8) al2s8[(size_t)i * 8 + k] = ps;
            else       al2s9[i] = ps;
            al2d[(size_t)i * 9 + k] = pd;
        }
    }
    union { _Float16 h[8]; uint4 u; } pk;
#pragma unroll
    for (int k = 0; k < 8; ++k) pk.h[k] = (_Float16)h2[k];
    H2a[(size_t)i * DD + lane] = pk.u;
    H2b[(size_t)i * DD + lane] = (_Float16)h2[8];
}

// ---- layer2: 16-lane groups, 4 edges per wave-iteration, dims q+16j ----
__global__ __launch_bounds__(256) void k_l2(
    const int* __restrict__ off, const int* __restrict__ csrc,
    const float* __restrict__ al2s8, const float* __restrict__ al2s9,
    const float* __restrict__ al2d,
    const uint4* __restrict__ H2a, const _Float16* __restrict__ H2b,
    float* __restrict__ out) {
    const int lane = threadIdx.x & 63;
    const int i = blockIdx.x * 4 + (threadIdx.x >> 6);
    const int g = lane >> 4, q = lane & 15;
    const int p0 = RFL(off[i]);
    const int p1 = RFL(off[i + 1]);
    float adv[9];
#pragma unroll
    for (int k = 0; k < 9; ++k) adv[k] = al2d[(size_t)i * 9 + k];

    float4 n4[9]; float den[9];
#pragma unroll
    for (int k = 0; k < 9; ++k) { n4[k] = make_float4(0.f, 0.f, 0.f, 0.f); den[k] = 0.f; }

    for (int p = p0; p < p1; p += 4) {
        int e = p + g;
        float mask = 1.f;
        if (e >= p1) { e = p1 - 1; mask = 0.f; }
        int s = csrc[e];                              // group-uniform broadcast
        const float4* pa = (const float4*)(al2s8 + (size_t)s * 8);
        float4 A0 = pa[0], A1 = pa[1];
        float A9 = al2s9[s];
        float as[9] = {A0.x, A0.y, A0.z, A0.w, A1.x, A1.y, A1.z, A1.w, A9};
        float w[9];
#pragma unroll
        for (int k = 0; k < 9; ++k) {
            float z = as[k] + adv[k];
            float lr = z > 0.f ? z : NEG * z;
            w[k] = __expf(lr) * mask;
            den[k] += w[k];
        }
        const uint4* rowa = H2a + (size_t)s * DD;
        const _Float16* rowb = H2b + (size_t)s * DD;
        union { uint4 v; _Float16 h[8]; } c0, c1, c2, c3;
        c0.v = rowa[q];       c1.v = rowa[q + 16];
        c2.v = rowa[q + 32];  c3.v = rowa[q + 48];
        float b0 = (float)rowb[q],      b1 = (float)rowb[q + 16];
        float b2 = (float)rowb[q + 32], b3 = (float)rowb[q + 48];
#pragma unroll
        for (int k = 0; k < 8; ++k) {
            n4[k].x = fmaf(w[k], (float)c0.h[k], n4[k].x);
            n4[k].y = fmaf(w[k], (float)c1.h[k], n4[k].y);
            n4[k].z = fmaf(w[k], (float)c2.h[k], n4[k].z);
            n4[k].w = fmaf(w[k], (float)c3.h[k], n4[k].w);
        }
        n4[8].x = fmaf(w[8], b0, n4[8].x);
        n4[8].y = fmaf(w[8], b1, n4[8].y);
        n4[8].z = fmaf(w[8], b2, n4[8].z);
        n4[8].w = fmaf(w[8], b3, n4[8].w);
    }
    // reduce across groups
#pragma unroll
    for (int k = 0; k < 9; ++k) {
#pragma unroll
        for (int o = 16; o <= 32; o <<= 1) {
            n4[k].x += __shfl_xor(n4[k].x, o);
            n4[k].y += __shfl_xor(n4[k].y, o);
            n4[k].z += __shfl_xor(n4[k].z, o);
            n4[k].w += __shfl_xor(n4[k].w, o);
            den[k]  += __shfl_xor(den[k], o);
        }
    }
    float4 o4 = make_float4(0.f, 0.f, 0.f, 0.f);
#pragma unroll
    for (int k = 0; k < 9; ++k) {
        if (den[k] > 0.f) {
            float inv = 1.f / den[k];
            o4.x = fmaf(n4[k].x, inv, o4.x);
            o4.y = fmaf(n4[k].y, inv, o4.y);
            o4.z = fmaf(n4[k].z, inv, o4.z);
            o4.w = fmaf(n4[k].w, inv, o4.w);
        }
    }
    if (lane < 16) {
        float* po = out + (size_t)i * DD;
        po[q]      = o4.x * (1.f / 9.f);
        po[q + 16] = o4.y * (1.f / 9.f);
        po[q + 32] = o4.z * (1.f / 9.f);
        po[q + 48] = o4.w * (1.f / 9.f);
    }
}

extern "C" void kernel_launch(void* const* d_in, const int* in_sizes, int n_in,
                              void* d_out, int out_size, void* d_ws, size_t ws_size,
                              hipStream_t stream) {
    const float* x   = (const float*)d_in[0];
    const int*   ei1 = (const int*)d_in[1];
    const int*   ei2 = (const int*)d_in[2];
    const float* W1  = (const float*)d_in[3];
    const float* a1s = (const float*)d_in[4];
    const float* a1d = (const float*)d_in[5];
    const float* W2  = (const float*)d_in[6];
    const float* a2s = (const float*)d_in[7];
    const float* a2d = (const float*)d_in[8];
    float* out = (float*)d_out;

    const int* src1 = ei1;
    const int* dst1 = ei1 + NE;
    const int* src2 = ei2;
    const int* dst2 = ei2 + NE;

    // ---- workspace layout (4-byte words), ~81.6 MB total ----
    uint4* H2a   = (uint4*)d_ws;                          // NN*64 uint4 (51.2 MB)
    float* H1    = (float*)d_ws + (size_t)NN * 256;       // NN*DD
    float* al1s  = H1 + (size_t)NN * DD;                  // NN
    float* al1d  = al1s + NN;                             // NN
    float* al2s8 = al1d + NN;                             // NN*8
    float* al2s9 = al2s8 + (size_t)NN * 8;                // NN
    float* al2d  = al2s9 + NN;                            // NN*9
    _Float16* H2b = (_Float16*)(al2d + (size_t)NN * 9);   // NN*DD halves
    int* off1 = (int*)((float*)H2b + (size_t)NN * DD / 2);// NN+1
    int* off2 = off1 + (NN + 1);                          // NN+1
    int* cnt1 = off2 + (NN + 1);                          // NN
    int* cnt2 = cnt1 + NN;                                // NN (contiguous with cnt1)
    int* csr1 = cnt2 + NN;                                // NE
    int* csr2 = csr1 + NE;                                // NE

    const int EB = 256, EG = (NE + EB - 1) / EB;
    const int NB = NN / 4;  // wave per node

    hipMemsetAsync(cnt1, 0, 2 * NN * sizeof(int), stream);
    k_hist<<<EG, EB, 0, stream>>>(dst1, dst2, cnt1, cnt2);
    k_scan<<<2, 1024, 0, stream>>>(cnt1, off1, cnt2, off2);
    hipMemsetAsync(cnt1, 0, 2 * NN * sizeof(int), stream);
    k_scatter<<<EG, EB, 0, stream>>>(src1, dst1, off1, cnt1, csr1,
                                     src2, dst2, off2, cnt2, csr2);
    k_h1<<<NB, 256, 0, stream>>>(x, W1, a1s, a1d, H1, al1s, al1d);

    k_l1<<<NB, 256, 0, stream>>>(off1, csr1, al1s, al1d, H1,
                                 W2, a2s, a2d, H2a, H2b, al2s8, al2s9, al2d);
    k_l2<<<NB, 256, 0, stream>>>(off2, csr2, al2s8, al2s9, al2d, H2a, H2b, out);
}

// Round 10
// 566.816 us; speedup vs baseline: 2.1816x; 2.1816x over previous
//
#include <hip/hip_runtime.h>
#include <hip/hip_bf16.h>

#define NN 50000
#define NE 800000
#define DD 64
#define NEG 0.2f

#define RFL(x) __builtin_amdgcn_readfirstlane(x)

// ---------------- CSR build ----------------
__global__ void k_hist(const int* __restrict__ dst1, const int* __restrict__ dst2,
                       int* __restrict__ cnt1, int* __restrict__ cnt2) {
    int e = blockIdx.x * blockDim.x + threadIdx.x;
    if (e < NE) {
        atomicAdd(&cnt1[dst1[e]], 1);
        atomicAdd(&cnt2[dst2[e]], 1);
    }
}

__global__ __launch_bounds__(1024) void k_scan(const int* __restrict__ cnt1, int* __restrict__ off1,
                                               const int* __restrict__ cnt2, int* __restrict__ off2) {
    const int* cnt = blockIdx.x ? cnt2 : cnt1;
    int* off = blockIdx.x ? off2 : off1;
    __shared__ int lds[1024];
    const int tid = threadIdx.x;
    const int CH = (NN + 1023) / 1024;  // 49
    const int base = tid * CH;
    int s = 0;
    for (int q = 0; q < CH; ++q) {
        int idx = base + q;
        if (idx < NN) s += cnt[idx];
    }
    lds[tid] = s;
    __syncthreads();
    for (int d = 1; d < 1024; d <<= 1) {
        int v = (tid >= d) ? lds[tid - d] : 0;
        __syncthreads();
        lds[tid] += v;
        __syncthreads();
    }
    int run = tid ? lds[tid - 1] : 0;
    for (int q = 0; q < CH; ++q) {
        int idx = base + q;
        if (idx < NN) { off[idx] = run; run += cnt[idx]; }
    }
    if (tid == 1023) off[NN] = lds[1023];
}

__global__ void k_scatter(const int* __restrict__ src1, const int* __restrict__ dst1,
                          const int* __restrict__ off1, int* __restrict__ fill1, int* __restrict__ csr1,
                          const int* __restrict__ src2, const int* __restrict__ dst2,
                          const int* __restrict__ off2, int* __restrict__ fill2, int* __restrict__ csr2) {
    int e = blockIdx.x * blockDim.x + threadIdx.x;
    if (e < NE) {
        int d1 = dst1[e];
        int p1 = off1[d1] + atomicAdd(&fill1[d1], 1);
        csr1[p1] = src1[e];
        int d2 = dst2[e];
        int p2 = off2[d2] + atomicAdd(&fill2[d2], 1);
        csr2[p2] = src2[e];
    }
}

// ---------------- H1 = x @ W1, alpha1 = H1 @ a1_{src,dst} ----------------
__global__ __launch_bounds__(256) void k_h1(
    const float* __restrict__ x, const float* __restrict__ W1,
    const float* __restrict__ a1s, const float* __restrict__ a1d,
    float* __restrict__ H1, float* __restrict__ al1s, float* __restrict__ al1d) {
    const int lane = threadIdx.x & 63;
    const int i = blockIdx.x * 4 + (threadIdx.x >> 6);
    const float xv = x[i * DD + lane];
    float h = 0.f;
#pragma unroll
    for (int j = 0; j < DD; ++j) h = fmaf(__shfl(xv, j), W1[j * DD + lane], h);
    H1[i * DD + lane] = h;
    float ps = h * a1s[lane], pd = h * a1d[lane];
#pragma unroll
    for (int o = 32; o; o >>= 1) { ps += __shfl_xor(ps, o); pd += __shfl_xor(pd, o); }
    if (lane == 0) { al1s[i] = ps; al1d[i] = pd; }
}

// ---------------- t2s = W2 @ a2s, t2d = W2 @ a2d (64 each) ----------------
__global__ void k_a2t(const float* __restrict__ W2, const float* __restrict__ a2s,
                      const float* __restrict__ a2d, float* __restrict__ t2s,
                      float* __restrict__ t2d) {
    int j = threadIdx.x & 63;
    float ss = 0.f, sd = 0.f;
#pragma unroll
    for (int d = 0; d < DD; ++d) {
        float w = W2[j * DD + d];
        ss = fmaf(w, a2s[d], ss);
        sd = fmaf(w, a2d[d], sd);
    }
    t2s[j] = ss;
    t2d[j] = sd;
}

// ---- layer1, all 9 steps: aggregate + ELU; NO W2 (pulled out by linearity) ----
// stores hm packed fp16: H2a = steps 1..8 [i][lane], H2b = step 9 [i][lane]
// alpha2 scores via precomputed t2s/t2d: al2s[k] = sum_d hm[k][d]*t2s[d]
__global__ __launch_bounds__(256) void k_l1(
    const int* __restrict__ off, const int* __restrict__ csrc,
    const float* __restrict__ al1s, const float* __restrict__ al1d,
    const float* __restrict__ H1,
    const float* __restrict__ t2s, const float* __restrict__ t2d,
    uint4* __restrict__ H2a, _Float16* __restrict__ H2b,
    float* __restrict__ al2s8, float* __restrict__ al2s9, float* __restrict__ al2d) {
    const int lane = threadIdx.x & 63;
    const int i = blockIdx.x * 4 + (threadIdx.x >> 6);
    const int p0 = RFL(off[i]);
    const int p1 = RFL(off[i + 1]);
    const float adv = al1d[i];
    float num[9], den[9];
#pragma unroll
    for (int k = 0; k < 9; ++k) { num[k] = 0.f; den[k] = 0.f; }

    auto edge = [&](int p) {
        int s = RFL(csrc[p]);
        float hv = H1[(size_t)s * DD + lane];
        float z = al1s[s] + adv;
        float c = z > 0.f ? z : NEG * z;           // leaky_relu, step-invariant
        float r = __expf(c * (1.f / 9.f));         // w_k = r^k
        float w = r;
#pragma unroll
        for (int k = 0; k < 9; ++k) { den[k] += w; num[k] = fmaf(w, hv, num[k]); w *= r; }
    };
    int p = p0;
    for (; p + 1 < p1; p += 2) { edge(p); edge(p + 1); }
    if (p < p1) edge(p);

    const float tss = t2s[lane];
    const float tdd = t2d[lane];
    float hm[9];
#pragma unroll
    for (int k = 0; k < 9; ++k) {
        float t = (float)(k + 1) * (1.f / 9.f);
        float v = (den[k] > 0.f) ? (t * num[k] / den[k]) : 0.f;
        hm[k] = (v > 0.f) ? v : expm1f(v);         // ELU
    }
#pragma unroll
    for (int k = 0; k < 9; ++k) {
        float ps = hm[k] * tss, pd = hm[k] * tdd;
#pragma unroll
        for (int o = 32; o; o >>= 1) { ps += __shfl_xor(ps, o); pd += __shfl_xor(pd, o); }
        if (lane == 0) {
            if (k < 8) al2s8[(size_t)i * 8 + k] = ps;
            else       al2s9[i] = ps;
            al2d[(size_t)i * 9 + k] = pd;
        }
    }
    union { _Float16 h[8]; uint4 u; } pk;
#pragma unroll
    for (int k = 0; k < 8; ++k) pk.h[k] = (_Float16)hm[k];
    H2a[(size_t)i * DD + lane] = pk.u;
    H2b[(size_t)i * DD + lane] = (_Float16)hm[8];
}

// ---- layer2: aggregate hm over edges, then ONE W2 matvec per node ----
__global__ __launch_bounds__(256) void k_l2(
    const int* __restrict__ off, const int* __restrict__ csrc,
    const float* __restrict__ al2s8, const float* __restrict__ al2s9,
    const float* __restrict__ al2d,
    const uint4* __restrict__ H2a, const _Float16* __restrict__ H2b,
    const float* __restrict__ W2, float* __restrict__ out) {
    const int lane = threadIdx.x & 63;
    const int i = blockIdx.x * 4 + (threadIdx.x >> 6);
    const int p0 = RFL(off[i]);
    const int p1 = RFL(off[i + 1]);
    float adv[9];
#pragma unroll
    for (int k = 0; k < 9; ++k) adv[k] = al2d[(size_t)i * 9 + k];
    float num[9], den[9];
#pragma unroll
    for (int k = 0; k < 9; ++k) { num[k] = 0.f; den[k] = 0.f; }

    auto edge = [&](int p) {
        int s = RFL(csrc[p]);
        uint4 u = H2a[(size_t)s * DD + lane];
        float h9 = (float)H2b[(size_t)s * DD + lane];
        const float4* pa = (const float4*)(al2s8 + (size_t)s * 8);
        float4 A0 = pa[0], A1 = pa[1];
        float A9 = al2s9[s];
        union { uint4 v; _Float16 h[8]; } c; c.v = u;
        float as[8] = {A0.x, A0.y, A0.z, A0.w, A1.x, A1.y, A1.z, A1.w};
#pragma unroll
        for (int k = 0; k < 8; ++k) {
            float z = as[k] + adv[k];
            float lr = z > 0.f ? z : NEG * z;
            float w = __expf(lr);
            den[k] += w;
            num[k] = fmaf(w, (float)c.h[k], num[k]);
        }
        float z = A9 + adv[8];
        float lr = z > 0.f ? z : NEG * z;
        float w = __expf(lr);
        den[8] += w;
        num[8] = fmaf(w, h9, num[8]);
    };
    int p = p0;
    for (; p + 1 < p1; p += 2) { edge(p); edge(p + 1); }
    if (p < p1) edge(p);

    // vsum[lane] = sum_k num[k]/den[k]  (attention-aggregated hm, summed over steps)
    float vsum = 0.f;
#pragma unroll
    for (int k = 0; k < 9; ++k) vsum += (den[k] > 0.f) ? (num[k] / den[k]) : 0.f;
    // out = (1/9) * W2^T-applied: out[d] = sum_j vsum[j] * W2[j][d]
    float h2 = 0.f;
#pragma unroll 8
    for (int j = 0; j < DD; ++j) h2 = fmaf(__shfl(vsum, j), W2[j * DD + lane], h2);
    out[(size_t)i * DD + lane] = h2 * (1.f / 9.f);
}

extern "C" void kernel_launch(void* const* d_in, const int* in_sizes, int n_in,
                              void* d_out, int out_size, void* d_ws, size_t ws_size,
                              hipStream_t stream) {
    const float* x   = (const float*)d_in[0];
    const int*   ei1 = (const int*)d_in[1];
    const int*   ei2 = (const int*)d_in[2];
    const float* W1  = (const float*)d_in[3];
    const float* a1s = (const float*)d_in[4];
    const float* a1d = (const float*)d_in[5];
    const float* W2  = (const float*)d_in[6];
    const float* a2s = (const float*)d_in[7];
    const float* a2d = (const float*)d_in[8];
    float* out = (float*)d_out;

    const int* src1 = ei1;
    const int* dst1 = ei1 + NE;
    const int* src2 = ei2;
    const int* dst2 = ei2 + NE;

    // ---- workspace layout (4-byte words), ~81.6 MB total ----
    uint4* H2a   = (uint4*)d_ws;                          // NN*64 uint4 (51.2 MB)
    float* H1    = (float*)d_ws + (size_t)NN * 256;       // NN*DD
    float* al1s  = H1 + (size_t)NN * DD;                  // NN
    float* al1d  = al1s + NN;                             // NN
    float* al2s8 = al1d + NN;                             // NN*8
    float* al2s9 = al2s8 + (size_t)NN * 8;                // NN
    float* al2d  = al2s9 + NN;                            // NN*9
    _Float16* H2b = (_Float16*)(al2d + (size_t)NN * 9);   // NN*DD halves
    int* off1 = (int*)((float*)H2b + (size_t)NN * DD / 2);// NN+1
    int* off2 = off1 + (NN + 1);                          // NN+1
    int* cnt1 = off2 + (NN + 1);                          // NN
    int* cnt2 = cnt1 + NN;                                // NN (contiguous with cnt1)
    int* csr1 = cnt2 + NN;                                // NE
    int* csr2 = csr1 + NE;                                // NE
    float* t2s = (float*)(csr2 + NE);                     // 64
    float* t2d = t2s + DD;                                // 64

    const int EB = 256, EG = (NE + EB - 1) / EB;
    const int NB = NN / 4;  // wave per node

    hipMemsetAsync(cnt1, 0, 2 * NN * sizeof(int), stream);
    k_hist<<<EG, EB, 0, stream>>>(dst1, dst2, cnt1, cnt2);
    k_scan<<<2, 1024, 0, stream>>>(cnt1, off1, cnt2, off2);
    hipMemsetAsync(cnt1, 0, 2 * NN * sizeof(int), stream);
    k_scatter<<<EG, EB, 0, stream>>>(src1, dst1, off1, cnt1, csr1,
                                     src2, dst2, off2, cnt2, csr2);
    k_h1<<<NB, 256, 0, stream>>>(x, W1, a1s, a1d, H1, al1s, al1d);
    k_a2t<<<1, 64, 0, stream>>>(W2, a2s, a2d, t2s, t2d);

    k_l1<<<NB, 256, 0, stream>>>(off1, csr1, al1s, al1d, H1,
                                 t2s, t2d, H2a, H2b, al2s8, al2s9, al2d);
    k_l2<<<NB, 256, 0, stream>>>(off2, csr2, al2s8, al2s9, al2d, H2a, H2b, W2, out);
}